// Round 1
// baseline (575.334 us; speedup 1.0000x reference)
//
#include <hip/hip_runtime.h>
#include <math.h>

// HydraChannelMixer fused kernel, MI355X (gfx950).
// Shapes (fixed by setup_inputs): B=64, C=21, P=96, D=256, R=32, H=64.
// One block per bp-row (bp = b*P + p), 256 threads, whole [C][D] tile in LDS.

#define DD 256
#define CC 21
#define RR 32
#define HH 64
#define PP 96
#define BB 64
#define NBP (BB * PP)   // 6144 blocks
#define NT 256

__device__ __forceinline__ float gelu_exact(float x) {
    // jax.nn.gelu(approximate=False): 0.5*x*(1+erf(x/sqrt(2)))
    return 0.5f * x * (1.0f + erff(x * 0.70710678118654752440f));
}
__device__ __forceinline__ float sigmoidf_(float x) {
    return 1.0f / (1.0f + __expf(-x));
}

extern "C" __global__ __launch_bounds__(NT, 2)
void hydra_fused(const float* __restrict__ x,
                 const float* __restrict__ ln_w, const float* __restrict__ ln_b,
                 const float* __restrict__ Wd,   const float* __restrict__ bd,
                 const float* __restrict__ Wq,   const float* __restrict__ Wk,
                 const float* __restrict__ Wv,   const float* __restrict__ Wg,
                 const float* __restrict__ bg,
                 const float* __restrict__ Wu,   const float* __restrict__ bu,
                 const float* __restrict__ cn1w, const float* __restrict__ cn1b,
                 const float* __restrict__ cn2w, const float* __restrict__ cn2b,
                 const float* __restrict__ dn1w, const float* __restrict__ dn1b,
                 const float* __restrict__ dn2w, const float* __restrict__ dn2b,
                 const float* __restrict__ eps_p,
                 float* __restrict__ out)
{
    __shared__ __align__(16) float sh_h[CC][DD];     // 21.0 KB  original h tile (residual + stats)
    __shared__ __align__(16) float sh_w[RR * DD];    // 32.0 KB  Wd' = ln_w*Wd ([k][r]) then Wu ([r][d])
    __shared__ __align__(16) float sh_M[CC][RR];     // K*V products, then final M = Qn*gate*gf
    __shared__ __align__(16) float sh_low[CC][RR];   // h_low, then Qn*gate
    __shared__ float sh_mu[CC];
    __shared__ float sh_rs[CC];
    __shared__ float sh_cv[DD];                      // chan_var (unbiased over C)
    __shared__ float sh_gate[DD];                    // adaptive gate value per d
    __shared__ float sh_gf[RR];                      // global_feat
    __shared__ float sh_red[NT];                     // cross-wave reduction scratch
    __shared__ float sh_h1[HH];                      // data-MLP hidden (gelu)
    __shared__ float sh_clh[HH];                     // channel-MLP hidden (gelu)
    __shared__ float sh_s1[RR];                      // sum_d ln_w[d]*Wd[d][r]
    __shared__ float sh_s2[RR];                      // sum_d ln_b[d]*Wd[d][r] + bd[r]

    const int t  = threadIdx.x;
    const int bp = blockIdx.x;
    const int b  = bp / PP;
    const int p  = bp - b * PP;
    // x[(b*C+c)*P*D + p*D + d]; per-c stride P*D
    const float* xbase = x + ((size_t)b * CC * PP + p) * DD;

    // ---------------- Phase 1: load h tile, stage Wd', per-r LN constants ----
    for (int i = t; i < CC * DD; i += NT) {
        int c = i >> 8, d = i & 255;
        sh_h[c][d] = xbase[(size_t)c * (PP * DD) + d];   // coalesced: 1 KB per c-row
    }
    for (int i = t; i < RR * DD; i += NT) {
        int k = i >> 5;                                   // i = k*32 + r
        sh_w[i] = ln_w[k] * Wd[i];                        // Wd' fused with ln scale
    }
    if (t < RR) {
        float s1 = 0.f, s2 = 0.f;
        for (int d = 0; d < DD; ++d) {
            float w = Wd[d * RR + t];                     // lanes r: coalesced 128B rows
            s1 += ln_w[d] * w;
            s2 += ln_b[d] * w;
        }
        sh_s1[t] = s1;
        sh_s2[t] = s2 + bd[t];
    }
    __syncthreads();

    // ---------------- Phase 2: LN stats per channel + channel variance per d -
    {
        const int w = t >> 6, lane = t & 63;
        for (int c = w; c < CC; c += 4) {
            float v0 = sh_h[c][lane      ], v1 = sh_h[c][lane +  64];
            float v2 = sh_h[c][lane + 128], v3 = sh_h[c][lane + 192];
            float s  = v0 + v1 + v2 + v3;
            float s2 = v0*v0 + v1*v1 + v2*v2 + v3*v3;
            for (int m = 32; m >= 1; m >>= 1) {
                s  += __shfl_xor(s,  m);
                s2 += __shfl_xor(s2, m);
            }
            if (lane == 0) {
                float mu  = s  * (1.0f / DD);
                float var = s2 * (1.0f / DD) - mu * mu;   // biased (jnp.var default)
                sh_mu[c] = mu;
                sh_rs[c] = rsqrtf(var + 1e-5f);
            }
        }
        // unbiased variance over C for each d (thread t = d); column reads conflict-free
        float cs = 0.f, cs2 = 0.f;
        #pragma unroll
        for (int c = 0; c < CC; ++c) { float v = sh_h[c][t]; cs += v; cs2 += v * v; }
        sh_cv[t] = (cs2 - cs * cs * (1.0f / CC)) * (1.0f / (CC - 1));
    }
    __syncthreads();

    // ---------------- Phase 3a: MLP hiddens (channel-MLP + data-MLP layer 1) -
    if (t < HH) {
        const float lc = 0.44073977f;                     // log(21)/log(1000)
        sh_clh[t] = gelu_exact(lc * cn1w[t] + cn1b[t]);
    }
    {
        const int w = t >> 6, j = t & 63;                 // K split over 4 waves
        const int k0 = w * 64;
        float acc = 0.f;
        for (int k = 0; k < 64; ++k)
            acc += sh_cv[k0 + k] * dn1w[(k0 + k) * HH + j];  // dn1 rows coalesced
        sh_red[t] = acc;
    }
    __syncthreads();
    if (t < HH) {
        float s = sh_red[t] + sh_red[t + 64] + sh_red[t + 128] + sh_red[t + 192] + dn1b[t];
        sh_h1[t] = gelu_exact(s);
    }
    __syncthreads();

    // ---------------- Phase 3c: adaptive gate per d (thread t = d) -----------
    {
        const float eps = eps_p[0];
        float a1 = 0.f, a2 = 0.f;
        #pragma unroll 8
        for (int j = 0; j < HH; ++j) {
            a1 += sh_h1[j]  * dn2w[j * DD + t];           // coalesced rows
            a2 += sh_clh[j] * cn2w[j * DD + t];
        }
        sh_gate[t] = sigmoidf_((a2 + cn2b[t]) + eps * (a1 + dn2b[t]));
    }
    // no barrier needed: phase 4 doesn't touch sh_gate; later barriers cover phase 6.

    // ---------------- Phase 4: h_low = LN(h) @ Wd + bd  (fused-LN form) ------
    {
        const int r  = t & 31;
        const int c0 = t >> 5;                            // 0..7; channels c0, c0+8, c0+16
        const int nc = (c0 + 16 < CC) ? 3 : 2;
        const float* hr0 = sh_h[c0];
        const float* hr1 = sh_h[c0 + 8];
        const float* hr2 = sh_h[(nc == 3) ? (c0 + 16) : 0];
        float a0 = 0.f, a1 = 0.f, a2 = 0.f;
        for (int k = 0; k < DD; k += 4) {
            float4 h0 = *(const float4*)(hr0 + k);        // broadcast reads (2-way: free)
            float4 h1 = *(const float4*)(hr1 + k);
            float4 h2 = *(const float4*)(hr2 + k);
            float w0 = sh_w[(k    ) * RR + r];            // row reads: conflict-free
            float w1 = sh_w[(k + 1) * RR + r];
            float w2 = sh_w[(k + 2) * RR + r];
            float w3 = sh_w[(k + 3) * RR + r];
            a0 += h0.x * w0 + h0.y * w1 + h0.z * w2 + h0.w * w3;
            a1 += h1.x * w0 + h1.y * w1 + h1.z * w2 + h1.w * w3;
            a2 += h2.x * w0 + h2.y * w1 + h2.z * w2 + h2.w * w3;
        }
        const float s1 = sh_s1[r], s2 = sh_s2[r];
        sh_low[c0    ][r] = sh_rs[c0    ] * (a0 - sh_mu[c0    ] * s1) + s2;
        sh_low[c0 + 8][r] = sh_rs[c0 + 8] * (a1 - sh_mu[c0 + 8] * s1) + s2;
        if (nc == 3)
            sh_low[c0 + 16][r] = sh_rs[c0 + 16] * (a2 - sh_mu[c0 + 16] * s1) + s2;
    }
    __syncthreads();

    // ---------------- Phase 5: QKVG + hydra pooling + content gate -----------
    // Re-stage sh_w with Wu ([r][d]) — safe: Wd' reads completed at the barrier.
    for (int i = t; i < RR * DD; i += NT) sh_w[i] = Wu[i];
    {
        const int r  = t & 31;
        const int c0 = t >> 5;
        const int nc = (c0 + 16 < CC) ? 3 : 2;
        float qg[3], kv[3];
        for (int i = 0; i < nc; ++i) {
            const int c = c0 + 8 * i;
            float q = 0.f, kk = 0.f, v = 0.f, g = 0.f;
            #pragma unroll 8
            for (int j = 0; j < RR; ++j) {
                float hl = sh_low[c][j];                  // broadcast
                q  += hl * Wq[j * RR + r];                // coalesced 128B rows (L1-hot)
                kk += hl * Wk[j * RR + r];
                v  += hl * Wv[j * RR + r];
                g  += hl * Wg[j * RR + r];
            }
            // row L2-norms over r: reduce across the 32-lane group holding this c
            float qn2 = q * q, kn2 = kk * kk;
            for (int m = 16; m >= 1; m >>= 1) {
                qn2 += __shfl_xor(qn2, m);
                kn2 += __shfl_xor(kn2, m);
            }
            float qn = q  / fmaxf(sqrtf(qn2), 1e-12f);
            float kn = kk / fmaxf(sqrtf(kn2), 1e-12f);
            float gate_c = sigmoidf_(g + bg[r]);
            qg[i] = qn * gate_c;                          // Q * content-gate
            kv[i] = kn * v;                               // K * V (for global pool)
        }
        __syncthreads();                                  // sh_low reads done; Wu staged
        for (int i = 0; i < nc; ++i) {
            const int c = c0 + 8 * i;
            sh_low[c][r] = qg[i];
            sh_M[c][r]   = kv[i];
        }
    }
    __syncthreads();
    if (t < RR) {                                         // global_feat[r] = sum_c K*V
        float s = 0.f;
        #pragma unroll
        for (int c = 0; c < CC; ++c) s += sh_M[c][t];
        sh_gf[t] = s;
    }
    __syncthreads();
    {
        const int r  = t & 31;
        const int c0 = t >> 5;
        const int nc = (c0 + 16 < CC) ? 3 : 2;
        for (int i = 0; i < nc; ++i) {
            const int c = c0 + 8 * i;
            sh_M[c][r] = sh_low[c][r] * sh_gf[r];         // M = Qn*gate_c*global_feat
        }
    }
    __syncthreads();

    // ---------------- Phase 6: mixed = M @ Wu + bu; out = h + gate*mixed -----
    {
        const int d = t;
        float acc[CC];
        #pragma unroll
        for (int c = 0; c < CC; ++c) acc[c] = 0.f;
        #pragma unroll
        for (int r4 = 0; r4 < RR; r4 += 4) {
            float w0 = sh_w[(r4    ) * DD + d];           // lanes d: conflict-free
            float w1 = sh_w[(r4 + 1) * DD + d];
            float w2 = sh_w[(r4 + 2) * DD + d];
            float w3 = sh_w[(r4 + 3) * DD + d];
            #pragma unroll
            for (int c = 0; c < CC; ++c) {
                float4 m4 = *(const float4*)&sh_M[c][r4]; // broadcast b128
                acc[c] += m4.x * w0 + m4.y * w1 + m4.z * w2 + m4.w * w3;
            }
        }
        const float g   = sh_gate[d];
        const float bud = bu[d];
        float* obase = out + ((size_t)b * CC * PP + p) * DD + d;
        #pragma unroll
        for (int c = 0; c < CC; ++c) {
            obase[(size_t)c * (PP * DD)] = sh_h[c][d] + g * (acc[c] + bud);
        }
    }
}

extern "C" void kernel_launch(void* const* d_in, const int* in_sizes, int n_in,
                              void* d_out, int out_size, void* d_ws, size_t ws_size,
                              hipStream_t stream) {
    const float* x    = (const float*)d_in[0];
    const float* ln_w = (const float*)d_in[1];
    const float* ln_b = (const float*)d_in[2];
    const float* Wd   = (const float*)d_in[3];
    const float* bd   = (const float*)d_in[4];
    const float* Wq   = (const float*)d_in[5];
    const float* Wk   = (const float*)d_in[6];
    const float* Wv   = (const float*)d_in[7];
    const float* Wg   = (const float*)d_in[8];
    const float* bg   = (const float*)d_in[9];
    const float* Wu   = (const float*)d_in[10];
    const float* bu   = (const float*)d_in[11];
    const float* cn1w = (const float*)d_in[12];
    const float* cn1b = (const float*)d_in[13];
    const float* cn2w = (const float*)d_in[14];
    const float* cn2b = (const float*)d_in[15];
    const float* dn1w = (const float*)d_in[16];
    const float* dn1b = (const float*)d_in[17];
    const float* dn2w = (const float*)d_in[18];
    const float* dn2b = (const float*)d_in[19];
    const float* eps  = (const float*)d_in[20];
    float* out = (float*)d_out;

    hydra_fused<<<NBP, NT, 0, stream>>>(x, ln_w, ln_b, Wd, bd, Wq, Wk, Wv, Wg, bg,
                                        Wu, bu, cn1w, cn1b, cn2w, cn2b,
                                        dn1w, dn1b, dn2w, dn2b, eps, out);
}

// Round 2
// 401.301 us; speedup vs baseline: 1.4337x; 1.4337x over previous
//
#include <hip/hip_runtime.h>
#include <math.h>

// HydraChannelMixer, MI355X (gfx950). Round 2: bf16-MFMA for the three
// matmuls + weight-preprocess kernel (B-layout bf16 tiles in d_ws).
// Shapes: B=64, C=21, P=96, D=256, R=32, H=64. One block per bp-row.

#define DD 256
#define CC 21
#define RR 32
#define HH 64
#define PP 96
#define BB 64
#define PD (PP * DD)
#define NBP (BB * PP)     // 6144
#define NT 256

#define SH_STRIDE 260     // sh_h row stride (pad +4: 2-way bank alias = free)
#define LOW_STRIDE 36     // sh_low row stride
#define QK_STRIDE 132     // sh_qkvg row stride

// d_ws layout (bytes)
#define WS_WDB 0          // 8192 shorts: Wd' bf16, 16 tiles (kb*2+ni)*512
#define WS_W4B 16384      // 4096 shorts: [Wq|Wk|Wv|Wg] bf16, 8 tiles ni*512
#define WS_WUB 24576      // 8192 shorts: Wu bf16, 16 tiles ni*512
#define WS_S2  40960      // 32 f32: ln_b@Wd + bd
#define WS_LG  41088      // 256 f32: channel_logits

typedef __attribute__((ext_vector_type(8))) short bf16x8;   // 8 bf16 in 4 VGPRs
typedef __attribute__((ext_vector_type(4))) float f32x4;

__device__ __forceinline__ float gelu_exact(float x) {
    return 0.5f * x * (1.0f + erff(x * 0.70710678118654752440f));
}
__device__ __forceinline__ float sigmoidf_(float x) {
    return 1.0f / (1.0f + __expf(-x));
}
__device__ __forceinline__ short f2bf(float f) {            // RNE f32->bf16
    union { float f; unsigned u; } v; v.f = f;
    unsigned r = v.u + 0x7FFFu + ((v.u >> 16) & 1u);
    return (short)(unsigned short)(r >> 16);
}
// A-fragment: lane holds A[m][k0..k0+7] with affine (x*al+be) applied, bf16.
__device__ __forceinline__ bf16x8 pack_a_affine(const float* rowp, int k0,
                                                float al, float be) {
    float4 x0 = *(const float4*)(rowp + k0);
    float4 x1 = *(const float4*)(rowp + k0 + 4);
    bf16x8 a;
    a[0] = f2bf(fmaf(x0.x, al, be)); a[1] = f2bf(fmaf(x0.y, al, be));
    a[2] = f2bf(fmaf(x0.z, al, be)); a[3] = f2bf(fmaf(x0.w, al, be));
    a[4] = f2bf(fmaf(x1.x, al, be)); a[5] = f2bf(fmaf(x1.y, al, be));
    a[6] = f2bf(fmaf(x1.z, al, be)); a[7] = f2bf(fmaf(x1.w, al, be));
    return a;
}
__device__ __forceinline__ bf16x8 pack_a(const float* rowp, int k0) {
    float4 x0 = *(const float4*)(rowp + k0);
    float4 x1 = *(const float4*)(rowp + k0 + 4);
    bf16x8 a;
    a[0] = f2bf(x0.x); a[1] = f2bf(x0.y); a[2] = f2bf(x0.z); a[3] = f2bf(x0.w);
    a[4] = f2bf(x1.x); a[5] = f2bf(x1.y); a[6] = f2bf(x1.z); a[7] = f2bf(x1.w);
    return a;
}

// ---------------------------------------------------------------------------
// Preprocess: constant weights -> MFMA-B-layout bf16 tiles + s2' + logits.
// B-layout (16x16x32): lane l holds B[k=(l>>4)*8+j][n=tile_n0+(l&15)], j=0..7,
// stored as tile blocks of 512 shorts at offset tile*512 + l*8 (one b128/lane).
// ---------------------------------------------------------------------------
extern "C" __global__ __launch_bounds__(NT)
void hydra_preproc(const float* __restrict__ ln_w, const float* __restrict__ ln_b,
                   const float* __restrict__ Wd,   const float* __restrict__ bd,
                   const float* __restrict__ Wq,   const float* __restrict__ Wk,
                   const float* __restrict__ Wv,   const float* __restrict__ Wg,
                   const float* __restrict__ Wu,
                   const float* __restrict__ cn1w, const float* __restrict__ cn1b,
                   const float* __restrict__ cn2w, const float* __restrict__ cn2b,
                   short* __restrict__ WdB, short* __restrict__ W4B,
                   short* __restrict__ WuB, float* __restrict__ s2p,
                   float* __restrict__ logits)
{
    const int t = threadIdx.x, lane = t & 63, w = t >> 6, bid = blockIdx.x;
    const int q = lane >> 4, nl = lane & 15;

    if (bid < 4) {                       // WdB: 16 tiles, tile = kb*2 + ni
        int tile = bid * 4 + w;
        int kb = tile >> 1, ni = tile & 1;
        int kbase = kb * 32 + q * 8;
        int n = ni * 16 + nl;
        bf16x8 o;
        #pragma unroll
        for (int j = 0; j < 8; ++j) {
            int k = kbase + j;
            o[j] = f2bf(ln_w[k] * Wd[k * RR + n]);
        }
        *(bf16x8*)(WdB + tile * 512 + lane * 8) = o;
    } else if (bid < 6) {                // W4B: 8 tiles (K=32 single k-tile)
        int ni = (bid - 4) * 4 + w;
        int n = ni * 16 + nl;
        const float* Wsel = (n < 32) ? Wq : (n < 64) ? Wk : (n < 96) ? Wv : Wg;
        int nn = n & 31;
        bf16x8 o;
        #pragma unroll
        for (int j = 0; j < 8; ++j) {
            int k = q * 8 + j;
            o[j] = f2bf(Wsel[k * RR + nn]);
        }
        *(bf16x8*)(W4B + ni * 512 + lane * 8) = o;
    } else if (bid < 10) {               // WuB: 16 tiles
        int ni = (bid - 6) * 4 + w;
        int n = ni * 16 + nl;
        bf16x8 o;
        #pragma unroll
        for (int j = 0; j < 8; ++j) {
            int k = q * 8 + j;
            o[j] = f2bf(Wu[k * DD + n]);
        }
        *(bf16x8*)(WuB + ni * 512 + lane * 8) = o;
    } else {                             // s2' + channel logits
        __shared__ float clh[HH];
        if (t < RR) {
            float s = 0.f;
            for (int k = 0; k < DD; ++k) s += ln_b[k] * Wd[k * RR + t];
            s2p[t] = s + bd[t];
        }
        if (t < HH) {
            const float lc = 0.44073977f;        // log(21)/log(1000)
            clh[t] = gelu_exact(lc * cn1w[t] + cn1b[t]);
        }
        __syncthreads();
        float a = 0.f;
        #pragma unroll 8
        for (int j = 0; j < HH; ++j) a += clh[j] * cn2w[j * DD + t];
        logits[t] = a + cn2b[t];
    }
}

// ---------------------------------------------------------------------------
// Main fused kernel: one block per bp-row, 256 threads (4 waves).
// ---------------------------------------------------------------------------
extern "C" __global__ __launch_bounds__(NT, 3)
void hydra_fused(const float* __restrict__ x,
                 const float* __restrict__ bg,   const float* __restrict__ bu,
                 const float* __restrict__ dn1w, const float* __restrict__ dn1b,
                 const float* __restrict__ dn2w, const float* __restrict__ dn2b,
                 const float* __restrict__ eps_p,
                 const short* __restrict__ WdB,  const short* __restrict__ W4B,
                 const short* __restrict__ WuB,  const float* __restrict__ s2p,
                 const float* __restrict__ logits,
                 float* __restrict__ out)
{
    __shared__ __align__(16) float sh_h[CC * SH_STRIDE];      // 21.3 KB residual/stats
    __shared__ __align__(16) float sh_low[32 * LOW_STRIDE];   // 4.5 KB h_low -> M
    __shared__ __align__(16) float sh_qkvg[32 * QK_STRIDE];   // 16.5 KB Q|K|V|G (K->KV)
    __shared__ float sh_mu[32], sh_rs[32];
    __shared__ float sh_cv[DD];
    __shared__ float sh_gate[DD];
    __shared__ float sh_gf[RR];
    __shared__ float sh_red[NT];
    __shared__ float sh_h1[HH];

    const int t    = threadIdx.x;
    const int lane = t & 63;
    const int w    = t >> 6;
    const int quad = lane >> 4;
    const int nl   = lane & 15;
    const int bp = blockIdx.x;
    const int b  = bp / PP;
    const int p  = bp - b * PP;
    const float* xbase = x   + (size_t)b * CC * PD + (size_t)p * DD;
    float*       obase = out + (size_t)b * CC * PD + (size_t)p * DD;

    // ---- Phase 1: stage h tile (21 x 256 f32), coalesced 16B/lane ----------
    for (int i = t; i < CC * 64; i += NT) {
        int c = i >> 6, l = i & 63;
        float4 v = *(const float4*)(xbase + (size_t)c * PD + l * 4);
        *(float4*)(sh_h + c * SH_STRIDE + l * 4) = v;
    }
    __syncthreads();

    // ---- Phase 2: LN stats per channel + unbiased channel variance per d ---
    for (int c = w; c < CC; c += 4) {
        const float* row = sh_h + c * SH_STRIDE;
        float v0 = row[lane], v1 = row[lane + 64];
        float v2 = row[lane + 128], v3 = row[lane + 192];
        float s  = v0 + v1 + v2 + v3;
        float s2 = v0 * v0 + v1 * v1 + v2 * v2 + v3 * v3;
        for (int m = 32; m >= 1; m >>= 1) {
            s  += __shfl_xor(s,  m);
            s2 += __shfl_xor(s2, m);
        }
        if (lane == 0) {
            float mu  = s * (1.0f / DD);
            float var = s2 * (1.0f / DD) - mu * mu;
            sh_mu[c] = mu;
            sh_rs[c] = rsqrtf(var + 1e-5f);
        }
    }
    {
        float cs = 0.f, cs2 = 0.f;
        #pragma unroll
        for (int c = 0; c < CC; ++c) {
            float v = sh_h[c * SH_STRIDE + t];
            cs += v; cs2 += v * v;
        }
        sh_cv[t] = (cs2 - cs * cs * (1.0f / CC)) * (1.0f / (CC - 1));
    }
    __syncthreads();

    // ---- Phase 3: h_low = (h-mu)*rs @ Wd' + s2'  via MFMA;  dn1 partials ---
    {
        const int mi = w & 1, ni = w >> 1;      // one 16x16 tile per wave
        const int m  = mi * 16 + nl;            // A row for this lane
        const int mc = (m < CC) ? m : (CC - 1);
        const float al = (m < CC) ? sh_rs[m] : 0.f;
        const float be = (m < CC) ? (-sh_mu[m] * al) : 0.f;
        const float* rowp = sh_h + mc * SH_STRIDE;

        bf16x8 bfr[8];
        #pragma unroll
        for (int kb = 0; kb < 8; ++kb)
            bfr[kb] = *(const bf16x8*)(WdB + (kb * 2 + ni) * 512 + lane * 8);
        f32x4 acc = {0.f, 0.f, 0.f, 0.f};
        #pragma unroll
        for (int kb = 0; kb < 8; ++kb) {
            bf16x8 a = pack_a_affine(rowp, kb * 32 + quad * 8, al, be);
            acc = __builtin_amdgcn_mfma_f32_16x16x32_bf16(a, bfr[kb], acc, 0, 0, 0);
        }
        const int colg = ni * 16 + nl;          // C col for this lane
        const float s2v = s2p[colg];
        #pragma unroll
        for (int reg = 0; reg < 4; ++reg) {
            int rowg = mi * 16 + quad * 4 + reg;
            sh_low[rowg * LOW_STRIDE + colg] = acc[reg] + s2v;
        }
    }
    {   // dn1 partial: sh_red[t] = sum over 64 k's of cv*dn1w
        const int j = lane, k0 = w * 64;
        float acc = 0.f;
        #pragma unroll 8
        for (int k = 0; k < 64; ++k)
            acc += sh_cv[k0 + k] * dn1w[(k0 + k) * HH + j];
        sh_red[t] = acc;
    }
    __syncthreads();

    // ---- Phase 4: h1 = gelu(dn1);  QKVG = h_low @ [Wq|Wk|Wv|Wg] via MFMA ---
    if (t < HH)
        sh_h1[t] = gelu_exact(sh_red[t] + sh_red[t + 64] + sh_red[t + 128] +
                              sh_red[t + 192] + dn1b[t]);
    {
        const int mi = w & 1, nig = (w >> 1) * 4;   // 4 ni-tiles per wave
        const int m = mi * 16 + nl;
        const float* rowp = sh_low + m * LOW_STRIDE;
        bf16x8 a = pack_a(rowp, quad * 8);          // K=32: single k-tile
        bf16x8 bfr[4];
        #pragma unroll
        for (int i = 0; i < 4; ++i)
            bfr[i] = *(const bf16x8*)(W4B + (nig + i) * 512 + lane * 8);
        #pragma unroll
        for (int i = 0; i < 4; ++i) {
            f32x4 acc = {0.f, 0.f, 0.f, 0.f};
            acc = __builtin_amdgcn_mfma_f32_16x16x32_bf16(a, bfr[i], acc, 0, 0, 0);
            const int colg = (nig + i) * 16 + nl;
            #pragma unroll
            for (int reg = 0; reg < 4; ++reg) {
                int rowg = mi * 16 + quad * 4 + reg;
                sh_qkvg[rowg * QK_STRIDE + colg] = acc[reg];
            }
        }
    }
    __syncthreads();

    // ---- Phase 5: adaptive gate per d;  norms + content gate + K*V ---------
    {
        const float eps = eps_p[0];
        float a1 = 0.f;
        #pragma unroll 8
        for (int j = 0; j < HH; ++j) a1 += sh_h1[j] * dn2w[j * DD + t];
        sh_gate[t] = sigmoidf_(logits[t] + eps * (a1 + dn2b[t]));
    }
    const int r  = t & 31;
    const int c0 = t >> 5;
    const int nc = (c0 + 16 < CC) ? 3 : 2;
    float qg[3];
    {
        const float bgr = bg[r];
        for (int i = 0; i < nc; ++i) {
            const int c = c0 + 8 * i;
            const float* row = sh_qkvg + c * QK_STRIDE;
            float q = row[r], k = row[32 + r], v = row[64 + r], g = row[96 + r];
            float qn2 = q * q, kn2 = k * k;
            for (int m = 16; m >= 1; m >>= 1) {
                qn2 += __shfl_xor(qn2, m);
                kn2 += __shfl_xor(kn2, m);
            }
            float qn = q / fmaxf(sqrtf(qn2), 1e-12f);
            float kn = k / fmaxf(sqrtf(kn2), 1e-12f);
            qg[i] = qn * sigmoidf_(g + bgr);
            sh_qkvg[c * QK_STRIDE + 32 + r] = kn * v;   // overwrite K slot with K*V
        }
    }
    __syncthreads();

    // ---- Phase 6: global_feat[r] = sum_c K*V ------------------------------
    if (t < RR) {
        float s = 0.f;
        #pragma unroll
        for (int c = 0; c < CC; ++c) s += sh_qkvg[c * QK_STRIDE + 32 + t];
        sh_gf[t] = s;
    }
    __syncthreads();

    // ---- Phase 7: M = (Qn * gate_c) * gf  into sh_low (A operand of up-proj)
    for (int i = 0; i < nc; ++i) {
        const int c = c0 + 8 * i;
        sh_low[c * LOW_STRIDE + r] = qg[i] * sh_gf[r];
    }
    __syncthreads();

    // ---- Phase 8: mixed = M @ Wu;  out = h + gate*(mixed + bu) ------------
    {
        const int mi = w & 1, nig = (w >> 1) * 8;   // 8 ni-tiles per wave
        const int m = mi * 16 + nl;
        const float* rowp = sh_low + m * LOW_STRIDE;
        bf16x8 a = pack_a(rowp, quad * 8);          // K=32 single tile
        bf16x8 bfr[8];
        #pragma unroll
        for (int i = 0; i < 8; ++i)
            bfr[i] = *(const bf16x8*)(WuB + (nig + i) * 512 + lane * 8);
        f32x4 accv[8];
        #pragma unroll
        for (int i = 0; i < 8; ++i) {
            f32x4 z = {0.f, 0.f, 0.f, 0.f};
            accv[i] = __builtin_amdgcn_mfma_f32_16x16x32_bf16(a, bfr[i], z, 0, 0, 0);
        }
        #pragma unroll
        for (int i = 0; i < 8; ++i) {
            const int d  = (nig + i) * 16 + nl;
            const float gd  = sh_gate[d];
            const float bud = bu[d];
            #pragma unroll
            for (int reg = 0; reg < 4; ++reg) {
                int c = mi * 16 + quad * 4 + reg;
                if (c < CC) {
                    float hres = sh_h[c * SH_STRIDE + d];
                    obase[(size_t)c * PD + d] = hres + gd * (accv[i][reg] + bud);
                }
            }
        }
    }
}

extern "C" void kernel_launch(void* const* d_in, const int* in_sizes, int n_in,
                              void* d_out, int out_size, void* d_ws, size_t ws_size,
                              hipStream_t stream) {
    const float* x    = (const float*)d_in[0];
    const float* ln_w = (const float*)d_in[1];
    const float* ln_b = (const float*)d_in[2];
    const float* Wd   = (const float*)d_in[3];
    const float* bd   = (const float*)d_in[4];
    const float* Wq   = (const float*)d_in[5];
    const float* Wk   = (const float*)d_in[6];
    const float* Wv   = (const float*)d_in[7];
    const float* Wg   = (const float*)d_in[8];
    const float* bg   = (const float*)d_in[9];
    const float* Wu   = (const float*)d_in[10];
    const float* bu   = (const float*)d_in[11];
    const float* cn1w = (const float*)d_in[12];
    const float* cn1b = (const float*)d_in[13];
    const float* cn2w = (const float*)d_in[14];
    const float* cn2b = (const float*)d_in[15];
    const float* dn1w = (const float*)d_in[16];
    const float* dn1b = (const float*)d_in[17];
    const float* dn2w = (const float*)d_in[18];
    const float* dn2b = (const float*)d_in[19];
    const float* eps  = (const float*)d_in[20];
    float* out = (float*)d_out;

    char* ws = (char*)d_ws;
    short* WdB   = (short*)(ws + WS_WDB);
    short* W4B   = (short*)(ws + WS_W4B);
    short* WuB   = (short*)(ws + WS_WUB);
    float* s2p   = (float*)(ws + WS_S2);
    float* lg    = (float*)(ws + WS_LG);

    hydra_preproc<<<11, NT, 0, stream>>>(ln_w, ln_b, Wd, bd, Wq, Wk, Wv, Wg, Wu,
                                         cn1w, cn1b, cn2w, cn2b,
                                         WdB, W4B, WuB, s2p, lg);
    hydra_fused<<<NBP, NT, 0, stream>>>(x, bg, bu, dn1w, dn1b, dn2w, dn2b, eps,
                                        WdB, W4B, WuB, s2p, lg, out);
}

// Round 3
// 345.348 us; speedup vs baseline: 1.6660x; 1.1620x over previous
//
#include <hip/hip_runtime.h>
#include <math.h>

// HydraChannelMixer, MI355X (gfx950). Round 3: latency attack.
// - LDS 47KB -> ~17.6KB (bf16 h/low staging, no weight staging) -> 5 blocks/CU
// - 8 barriers -> 5; LN stats fused into load loop via VALU DPP reductions
// - dn1/dn2 weights pre-packed bf16x8 coalesced (8-16 b128 loads vs 64 b32)
// - direct ds_read_b128 MFMA A-frags (LN folded into C-fixup via s1/s2)
// Shapes: B=64, C=21, P=96, D=256, R=32, H=64. One block per bp-row.

#define DD 256
#define CC 21
#define RR 32
#define HH 64
#define PP 96
#define BB 64
#define PD (PP * DD)
#define NBP (BB * PP)     // 6144
#define NT 256

#define HBS 264           // hbf row stride (shorts): 528B, multiple of 16B
#define LWS 40            // lowbf row stride (shorts): 80B, multiple of 16B

// d_ws layout (bytes)
#define WS_WDB  0         // 8192 sh: Wd' bf16 B-frags, 16 tiles (kb*2+ni)*512
#define WS_W4B  16384     // 4096 sh: [Wq|Wk|Wv|Wg] bf16 B-frags, 8 tiles
#define WS_WUB  24576     // 8192 sh: Wu bf16 B-frags, 16 tiles
#define WS_DN1P 40960     // 16384 sh: dn1w^T packed bf16 [kb][j][8]
#define WS_DN2P 73728     // 16384 sh: dn2w packed bf16 [jb][d][8]
#define WS_S1   106496    // 32 f32: sum_k bf16(ln_w*Wd)[k][r]
#define WS_S2   106624    // 32 f32: ln_b@Wd + bd
#define WS_LG   106752    // 256 f32: channel_logits

typedef __attribute__((ext_vector_type(8))) short bf16x8;
typedef __attribute__((ext_vector_type(4))) float f32x4;
typedef __attribute__((ext_vector_type(4))) unsigned short u16x4;

__device__ __forceinline__ float gelu_exact(float x) {
    return 0.5f * x * (1.0f + erff(x * 0.70710678118654752440f));
}
__device__ __forceinline__ float sigmoidf_(float x) {
    return 1.0f / (1.0f + __expf(-x));
}
__device__ __forceinline__ short f2bf(float f) {            // RNE f32->bf16
    union { float f; unsigned u; } v; v.f = f;
    unsigned r = v.u + 0x7FFFu + ((v.u >> 16) & 1u);
    return (short)(unsigned short)(r >> 16);
}
__device__ __forceinline__ float bf2f_s(short s) {
    union { unsigned u; float f; } v; v.u = ((unsigned)(unsigned short)s) << 16;
    return v.f;
}

// DPP butterfly add: runs on VALU pipe (not LDS), ~2cyc issue each.
#define DPP_ADD(v, ctrl)                                                      \
    (v) += __builtin_bit_cast(float, __builtin_amdgcn_update_dpp(             \
               0, __builtin_bit_cast(int, (v)), (ctrl), 0xF, 0xF, true))

// all-lane sum over each contiguous 16-lane row: xor1, xor2, ror4, ror8
__device__ __forceinline__ float rowsum16(float v) {
    DPP_ADD(v, 0xB1);   // quad_perm(1,0,3,2) = xor1
    DPP_ADD(v, 0x4E);   // quad_perm(2,3,0,1) = xor2
    DPP_ADD(v, 0x124);  // row_ror:4
    DPP_ADD(v, 0x128);  // row_ror:8
    return v;
}
__device__ __forceinline__ float rdlane(float v, int l) {
    return __builtin_bit_cast(float,
        __builtin_amdgcn_readlane(__builtin_bit_cast(int, v), l));
}

// ---------------------------------------------------------------------------
// Preprocess (27 blocks): weights -> MFMA-B bf16 tiles, packed dn-MLP weights,
// s1/s2 LN-fold constants, constant channel logits.
// B-frag layout (16x16x32): lane l holds B[k=(l>>4)*8+j][n0+(l&15)], one b128.
// ---------------------------------------------------------------------------
extern "C" __global__ __launch_bounds__(NT)
void hydra_preproc(const float* __restrict__ ln_w, const float* __restrict__ ln_b,
                   const float* __restrict__ Wd,   const float* __restrict__ bd,
                   const float* __restrict__ Wq,   const float* __restrict__ Wk,
                   const float* __restrict__ Wv,   const float* __restrict__ Wg,
                   const float* __restrict__ Wu,
                   const float* __restrict__ cn1w, const float* __restrict__ cn1b,
                   const float* __restrict__ cn2w, const float* __restrict__ cn2b,
                   const float* __restrict__ dn1w, const float* __restrict__ dn2w,
                   short* __restrict__ WdB, short* __restrict__ W4B,
                   short* __restrict__ WuB, short* __restrict__ dn1P,
                   short* __restrict__ dn2P,
                   float* __restrict__ s1p, float* __restrict__ s2p,
                   float* __restrict__ logits)
{
    const int t = threadIdx.x, lane = t & 63, w = t >> 6, bid = blockIdx.x;
    const int q = lane >> 4, nl = lane & 15;

    if (bid < 4) {                       // WdB: 16 tiles, tile = kb*2 + ni
        int tile = bid * 4 + w;
        int kb = tile >> 1, ni = tile & 1;
        int kbase = kb * 32 + q * 8;
        int n = ni * 16 + nl;
        bf16x8 o;
        #pragma unroll
        for (int j = 0; j < 8; ++j) {
            int k = kbase + j;
            o[j] = f2bf(ln_w[k] * Wd[k * RR + n]);
        }
        *(bf16x8*)(WdB + tile * 512 + lane * 8) = o;
    } else if (bid < 6) {                // W4B: 8 tiles
        int ni = (bid - 4) * 4 + w;
        int n = ni * 16 + nl;
        const float* Wsel = (n < 32) ? Wq : (n < 64) ? Wk : (n < 96) ? Wv : Wg;
        int nn = n & 31;
        bf16x8 o;
        #pragma unroll
        for (int j = 0; j < 8; ++j) o[j] = f2bf(Wsel[(q * 8 + j) * RR + nn]);
        *(bf16x8*)(W4B + ni * 512 + lane * 8) = o;
    } else if (bid < 10) {               // WuB: 16 tiles
        int ni = (bid - 6) * 4 + w;
        int n = ni * 16 + nl;
        bf16x8 o;
        #pragma unroll
        for (int j = 0; j < 8; ++j) o[j] = f2bf(Wu[(q * 8 + j) * DD + n]);
        *(bf16x8*)(WuB + ni * 512 + lane * 8) = o;
    } else if (bid == 10) {              // s1, s2, channel logits
        __shared__ float red1[8][33], red2[8][33];
        __shared__ float clh[HH];
        int r = t & 31, ks = t >> 5;
        float a1 = 0.f, a2 = 0.f;
        for (int k = ks * 32; k < ks * 32 + 32; ++k) {
            float wv = Wd[k * RR + r];
            a1 += bf2f_s(f2bf(ln_w[k] * wv));   // match MFMA's bf16-rounded B
            a2 += ln_b[k] * wv;
        }
        red1[ks][r] = a1; red2[ks][r] = a2;
        if (t < HH) {
            const float lc = 0.44073977f;       // log(21)/log(1000)
            clh[t] = gelu_exact(lc * cn1w[t] + cn1b[t]);
        }
        __syncthreads();
        if (t < RR) {
            float s1 = 0.f, s2 = 0.f;
            #pragma unroll
            for (int s = 0; s < 8; ++s) { s1 += red1[s][t]; s2 += red2[s][t]; }
            s1p[t] = s1;
            s2p[t] = s2 + bd[t];
        }
        float a = 0.f;
        #pragma unroll 8
        for (int j = 0; j < HH; ++j) a += clh[j] * cn2w[j * DD + t];
        logits[t] = a + cn2b[t];
    } else if (bid < 19) {               // dn1P: [kb][j][8], kb=0..31, j=0..63
        int slot = (bid - 11) * 256 + t; // 0..2047
        int kb = slot >> 6, j = slot & 63;
        bf16x8 o;
        #pragma unroll
        for (int ki = 0; ki < 8; ++ki) o[ki] = f2bf(dn1w[(kb * 8 + ki) * HH + j]);
        *(bf16x8*)(dn1P + slot * 8) = o;
    } else {                             // dn2P: [jb][d][8], jb=0..7, d=0..255
        int slot = (bid - 19) * 256 + t;
        int jb = slot >> 8, d = slot & 255;
        bf16x8 o;
        #pragma unroll
        for (int ji = 0; ji < 8; ++ji) o[ji] = f2bf(dn2w[(jb * 8 + ji) * DD + d]);
        *(bf16x8*)(dn2P + slot * 8) = o;
    }
}

// ---------------------------------------------------------------------------
// Main fused kernel: one block per bp-row, 256 threads (4 waves), 5 barriers.
// ---------------------------------------------------------------------------
extern "C" __global__ __launch_bounds__(NT, 5)
void hydra_fused(const float* __restrict__ x,
                 const float* __restrict__ bg,   const float* __restrict__ bu,
                 const float* __restrict__ dn1b, const float* __restrict__ dn2b,
                 const float* __restrict__ eps_p,
                 const short* __restrict__ WdB,  const short* __restrict__ W4B,
                 const short* __restrict__ WuB,  const short* __restrict__ dn1P,
                 const short* __restrict__ dn2P,
                 const float* __restrict__ s1p,  const float* __restrict__ s2p,
                 const float* __restrict__ logits,
                 float* __restrict__ out)
{
    __shared__ __align__(16) short  hbf[CC * HBS];    // 11,088 B  bf16 h tile
    __shared__ __align__(16) short  lowbf[32 * LWS];  //  2,560 B  h_low -> M
    __shared__ __align__(16) float  sh_cv[DD];        //  1,024 B
    __shared__ __align__(16) float2 murs[32];         //    256 B  (mu, rs)
    __shared__ __align__(16) float  dn1p[128];        //    512 B  dn1 partials
    __shared__ __align__(16) float  sh_h1[HH];        //    256 B
    __shared__ __align__(16) float  gfp[64];          //    256 B  gf partials
    __shared__ __align__(16) float  sh_gf[RR];        //    128 B
    __shared__ __align__(16) float  sh_gate[DD];      //  1,024 B

    const int t    = threadIdx.x;
    const int lane = t & 63;
    const int w    = t >> 6;
    const int quad = lane >> 4;
    const int nl   = lane & 15;
    const int bp = blockIdx.x;
    const int b  = bp / PP;
    const int p  = bp - b * PP;
    const float* xbase = x   + (size_t)b * CC * PD + (size_t)p * DD;
    float*       obase = out + (size_t)b * CC * PD + (size_t)p * DD;

    // ---- Phase 1: load h tile (wave w owns row iter*4+w), bf16 to LDS,
    //      LN stats per row via DPP butterflies (f32 precision from regs) ----
    if (t >= 21 && t < 32) murs[t] = make_float2(0.f, 0.f);
    #pragma unroll
    for (int iter = 0; iter < 6; ++iter) {
        int c = iter * 4 + w;
        bool act = (c < CC);
        float4 v = make_float4(0.f, 0.f, 0.f, 0.f);
        if (act) v = *(const float4*)(xbase + (size_t)c * PD + lane * 4);
        if (act) {
            u16x4 u;
            u[0] = (unsigned short)f2bf(v.x); u[1] = (unsigned short)f2bf(v.y);
            u[2] = (unsigned short)f2bf(v.z); u[3] = (unsigned short)f2bf(v.w);
            *(u16x4*)(hbf + c * HBS + lane * 4) = u;
        }
        float s  = v.x + v.y + v.z + v.w;
        float s2 = v.x * v.x + v.y * v.y + v.z * v.z + v.w * v.w;
        s  = rowsum16(s);
        s2 = rowsum16(s2);
        float tot  = rdlane(s, 0)  + rdlane(s, 16)  + rdlane(s, 32)  + rdlane(s, 48);
        float tot2 = rdlane(s2, 0) + rdlane(s2, 16) + rdlane(s2, 32) + rdlane(s2, 48);
        if (act && lane == 0) {
            float mu  = tot * (1.0f / DD);
            float var = tot2 * (1.0f / DD) - mu * mu;    // biased (LN)
            murs[c] = make_float2(mu, rsqrtf(var + 1e-5f));
        }
    }
    __syncthreads();   // B1

    // ---- Phase 2: channel variance (unbiased over C) + down-proj MFMA ------
    {
        float cs = 0.f, cs2 = 0.f;
        #pragma unroll
        for (int c = 0; c < CC; ++c) {
            float v = bf2f_s(hbf[c * HBS + t]);
            cs += v; cs2 += v * v;
        }
        sh_cv[t] = (cs2 - cs * cs * (1.0f / CC)) * (1.0f / (CC - 1));
    }
    {   // one 16x16 tile per wave: mi = w&1, ni = w>>1
        const int mi = w & 1, ni = w >> 1;
        const int m  = mi * 16 + nl;
        const int mc = (m < CC) ? m : (CC - 1);
        f32x4 acc = {0.f, 0.f, 0.f, 0.f};
        #pragma unroll
        for (int kb = 0; kb < 8; ++kb) {
            bf16x8 a  = *(const bf16x8*)(hbf + mc * HBS + kb * 32 + quad * 8);
            bf16x8 bw = *(const bf16x8*)(WdB + (kb * 2 + ni) * 512 + lane * 8);
            acc = __builtin_amdgcn_mfma_f32_16x16x32_bf16(a, bw, acc, 0, 0, 0);
        }
        const int colg = ni * 16 + nl;
        const float s1v = s1p[colg], s2v = s2p[colg];
        #pragma unroll
        for (int reg = 0; reg < 4; ++reg) {
            int rowg = mi * 16 + quad * 4 + reg;
            float2 mr = murs[rowg];                      // rows>=21: (0,0)
            float hl = mr.y * (acc[reg] - mr.x * s1v) + s2v;
            lowbf[rowg * LWS + colg] = f2bf(hl);
        }
    }
    __syncthreads();   // B2

    // ---- Phase 3: waves 0,2: QKVG MFMA + norms + content gate + KV pool;
    //               waves 1,3: dn1 (packed bf16, coalesced b128) -------------
    const int mi2 = w >> 1;
    float qg0[4], qg1[4];
    if ((w & 1) == 0) {
        const int m = mi2 * 16 + nl;
        bf16x8 a = *(const bf16x8*)(lowbf + m * LWS + quad * 8);
        f32x4 acc[8];
        #pragma unroll
        for (int i = 0; i < 8; ++i) {
            bf16x8 bw = *(const bf16x8*)(W4B + i * 512 + lane * 8);
            f32x4 z = {0.f, 0.f, 0.f, 0.f};
            acc[i] = __builtin_amdgcn_mfma_f32_16x16x32_bf16(a, bw, z, 0, 0, 0);
        }
        // tiles: 0,1=Q | 2,3=K | 4,5=V | 6,7=G ; lane cols nl and 16+nl
        const float bg0 = bg[nl], bg1 = bg[16 + nl];
        float kv0 = 0.f, kv1 = 0.f;
        #pragma unroll
        for (int reg = 0; reg < 4; ++reg) {
            float q0 = acc[0][reg], q1 = acc[1][reg];
            float k0 = acc[2][reg], k1 = acc[3][reg];
            float q2 = rowsum16(q0 * q0 + q1 * q1);      // sum over 32 cols
            float k2 = rowsum16(k0 * k0 + k1 * k1);
            float qi = 1.0f / fmaxf(sqrtf(q2), 1e-12f);
            float ki = 1.0f / fmaxf(sqrtf(k2), 1e-12f);
            float g0 = sigmoidf_(acc[6][reg] + bg0);
            float g1 = sigmoidf_(acc[7][reg] + bg1);
            qg0[reg] = q0 * qi * g0;
            qg1[reg] = q1 * qi * g1;
            int rowg = mi2 * 16 + quad * 4 + reg;
            float msk = (rowg < CC) ? 1.0f : 0.0f;
            kv0 += msk * (k0 * ki * acc[4][reg]);
            kv1 += msk * (k1 * ki * acc[5][reg]);
        }
        kv0 += __shfl_xor(kv0, 16); kv0 += __shfl_xor(kv0, 32);
        kv1 += __shfl_xor(kv1, 16); kv1 += __shfl_xor(kv1, 32);
        if (quad == 0) {
            gfp[mi2 * 32 + nl]      = kv0;
            gfp[mi2 * 32 + 16 + nl] = kv1;
        }
    } else {
        const int half = w >> 1;     // waves 1,3 split K over two halves
        float part = 0.f;
        #pragma unroll
        for (int i = 0; i < 16; ++i) {
            int kb = half * 16 + i;
            bf16x8 wv = *(const bf16x8*)(dn1P + (kb * 64 + lane) * 8);
            f32x4 c0 = *(const f32x4*)(sh_cv + kb * 8);
            f32x4 c1 = *(const f32x4*)(sh_cv + kb * 8 + 4);
            part += bf2f_s(wv[0]) * c0[0] + bf2f_s(wv[1]) * c0[1]
                  + bf2f_s(wv[2]) * c0[2] + bf2f_s(wv[3]) * c0[3]
                  + bf2f_s(wv[4]) * c1[0] + bf2f_s(wv[5]) * c1[1]
                  + bf2f_s(wv[6]) * c1[2] + bf2f_s(wv[7]) * c1[3];
        }
        dn1p[half * 64 + lane] = part;
    }
    __syncthreads();   // B3

    // ---- Phase 4: finalize h1 and global_feat ------------------------------
    if (t < HH) sh_h1[t] = gelu_exact(dn1p[t] + dn1p[64 + t] + dn1b[t]);
    if (t < RR) sh_gf[t] = gfp[t] + gfp[32 + t];
    __syncthreads();   // B4

    // ---- Phase 5: adaptive gate (dn2, packed bf16) + write M ---------------
    {
        const float eps = eps_p[0];
        float a1 = 0.f;
        #pragma unroll
        for (int jb = 0; jb < 8; ++jb) {
            bf16x8 wv = *(const bf16x8*)(dn2P + (jb * 256 + t) * 8);
            f32x4 h0 = *(const f32x4*)(sh_h1 + jb * 8);
            f32x4 h1 = *(const f32x4*)(sh_h1 + jb * 8 + 4);
            a1 += bf2f_s(wv[0]) * h0[0] + bf2f_s(wv[1]) * h0[1]
                + bf2f_s(wv[2]) * h0[2] + bf2f_s(wv[3]) * h0[3]
                + bf2f_s(wv[4]) * h1[0] + bf2f_s(wv[5]) * h1[1]
                + bf2f_s(wv[6]) * h1[2] + bf2f_s(wv[7]) * h1[3];
        }
        sh_gate[t] = sigmoidf_(logits[t] + eps * (a1 + dn2b[t]));
    }
    if ((w & 1) == 0) {              // M = (Qn*gate_c)*gf  (A of up-proj)
        float gf0 = sh_gf[nl], gf1 = sh_gf[16 + nl];
        #pragma unroll
        for (int reg = 0; reg < 4; ++reg) {
            int rowg = mi2 * 16 + quad * 4 + reg;
            lowbf[rowg * LWS + nl]      = f2bf(qg0[reg] * gf0);
            lowbf[rowg * LWS + 16 + nl] = f2bf(qg1[reg] * gf1);
        }
    }
    __syncthreads();   // B5

    // ---- Phase 6: mixed = M @ Wu; out = h + gate*(mixed + bu) --------------
    {
        const int mi = w & 1, nig = (w >> 1) * 8;
        const int m = mi * 16 + nl;
        bf16x8 a = *(const bf16x8*)(lowbf + m * LWS + quad * 8);
        #pragma unroll
        for (int i = 0; i < 8; ++i) {
            bf16x8 bw = *(const bf16x8*)(WuB + (nig + i) * 512 + lane * 8);
            f32x4 z = {0.f, 0.f, 0.f, 0.f};
            f32x4 acc = __builtin_amdgcn_mfma_f32_16x16x32_bf16(a, bw, z, 0, 0, 0);
            const int d   = (nig + i) * 16 + nl;
            const float gd  = sh_gate[d];
            const float bud = bu[d];
            #pragma unroll
            for (int reg = 0; reg < 4; ++reg) {
                int c = mi * 16 + quad * 4 + reg;
                if (c < CC) {
                    float hres = bf2f_s(hbf[c * HBS + d]);
                    obase[(size_t)c * PD + d] = hres + gd * (acc[reg] + bud);
                }
            }
        }
    }
}

extern "C" void kernel_launch(void* const* d_in, const int* in_sizes, int n_in,
                              void* d_out, int out_size, void* d_ws, size_t ws_size,
                              hipStream_t stream) {
    const float* x    = (const float*)d_in[0];
    const float* ln_w = (const float*)d_in[1];
    const float* ln_b = (const float*)d_in[2];
    const float* Wd   = (const float*)d_in[3];
    const float* bd   = (const float*)d_in[4];
    const float* Wq   = (const float*)d_in[5];
    const float* Wk   = (const float*)d_in[6];
    const float* Wv   = (const float*)d_in[7];
    const float* Wg   = (const float*)d_in[8];
    const float* bg   = (const float*)d_in[9];
    const float* Wu   = (const float*)d_in[10];
    const float* bu   = (const float*)d_in[11];
    const float* cn1w = (const float*)d_in[12];
    const float* cn1b = (const float*)d_in[13];
    const float* cn2w = (const float*)d_in[14];
    const float* cn2b = (const float*)d_in[15];
    const float* dn1w = (const float*)d_in[16];
    const float* dn1b = (const float*)d_in[17];
    const float* dn2w = (const float*)d_in[18];
    const float* dn2b = (const float*)d_in[19];
    const float* eps  = (const float*)d_in[20];
    float* out = (float*)d_out;

    char* ws = (char*)d_ws;
    short* WdB  = (short*)(ws + WS_WDB);
    short* W4B  = (short*)(ws + WS_W4B);
    short* WuB  = (short*)(ws + WS_WUB);
    short* dn1P = (short*)(ws + WS_DN1P);
    short* dn2P = (short*)(ws + WS_DN2P);
    float* s1p  = (float*)(ws + WS_S1);
    float* s2p  = (float*)(ws + WS_S2);
    float* lg   = (float*)(ws + WS_LG);

    hydra_preproc<<<27, NT, 0, stream>>>(ln_w, ln_b, Wd, bd, Wq, Wk, Wv, Wg, Wu,
                                         cn1w, cn1b, cn2w, cn2b, dn1w, dn2w,
                                         WdB, W4B, WuB, dn1P, dn2P, s1p, s2p, lg);
    hydra_fused<<<NBP, NT, 0, stream>>>(x, bg, bu, dn1b, dn2b, eps,
                                        WdB, W4B, WuB, dn1P, dn2P, s1p, s2p, lg,
                                        out);
}